// Round 6
// baseline (178.403 us; speedup 1.0000x reference)
//
#include <hip/hip_runtime.h>

// AttentionSinkRope — f32 shifted-copy + constant-angle re-rotation.
// R5 (177.8 us) + single-dispatch merge: grid (64+508, 128), per-block work
// byte-identical to R5's two kernels; branch on blockIdx.x is wave-uniform.
//
//   k_caches: [128 lh][128 d][4064 pos]   (pos contiguous)
//   v_caches: [128 lh][4064 pos][128 d]   (d contiguous)
//   rerotation_cos/sin: [3932][64]        (all rows identical)
//   out = new_k ++ new_v (float32), nontemporal throughout.

#define LH      128
#define DDIM    128
#define CLEN    4064
#define SINKN   4
#define KEEPEND 3936
#define SHIFT   128
#define KELEMS  66584576ull   // LH * DDIM * CLEN

typedef float f4 __attribute__((ext_vector_type(4)));

__device__ __forceinline__ f4 ntload4(const float* p) {
    return __builtin_nontemporal_load((const f4*)p);
}
__device__ __forceinline__ void ntstore4(float* p, f4 v) {
    __builtin_nontemporal_store(v, (f4*)p);
}

__global__ __launch_bounds__(256) void sinkrope_kernel(
    const float* __restrict__ k,
    const float* __restrict__ v,
    const float* __restrict__ rcos,
    const float* __restrict__ rsin,
    float* __restrict__ outk,
    float* __restrict__ outv)
{
    const int lh = blockIdx.y;

    if (blockIdx.x < 64) {
        // ---- K role: rows 2d, 2d+1 of (lh); positions contiguous ----
        const int rp = blockIdx.x;
        const size_t rowA = (size_t)lh * ((size_t)DDIM * CLEN) + (size_t)(2 * rp) * CLEN;
        const float* srcA = k + rowA;
        const float* srcB = srcA + CLEN;
        float* dstA = outk + rowA;
        float* dstB = dstA + CLEN;

        const float C = rcos[rp];        // table rows identical -> row 0
        const float S = rsin[rp];

        for (int chunk = threadIdx.x; chunk < 1016; chunk += 256) {
            const int c0 = chunk * 4;
            if (chunk >= 984) {
                f4 z = (f4)0.f;
                ntstore4(dstA + c0, z);
                ntstore4(dstB + c0, z);
            } else if (chunk == 0) {
                ntstore4(dstA, ntload4(srcA));
                ntstore4(dstB, ntload4(srcB));
            } else {
                f4 a = ntload4(srcA + c0 + SHIFT);
                f4 b = ntload4(srcB + c0 + SHIFT);
                f4 oa = a * C - b * S;
                f4 ob = a * S + b * C;
                ntstore4(dstA + c0, oa);
                ntstore4(dstB + c0, ob);
            }
        }
    } else {
        // ---- V role: one float4 chunk per thread; shift = +16384 elems ----
        const size_t base = (size_t)lh * ((size_t)CLEN * DDIM);
        const int idx = (blockIdx.x - 64) * 256 + threadIdx.x;  // < 130048
        const int row = idx >> 5;        // 32 chunks per row
        const size_t off = base + (size_t)idx * 4;
        f4 val;
        if (row < SINKN) {
            val = ntload4(v + off);
        } else if (row < KEEPEND) {
            val = ntload4(v + off + (size_t)SHIFT * DDIM);
        } else {
            val = (f4)0.f;
        }
        ntstore4(outv + off, val);
    }
}

extern "C" void kernel_launch(void* const* d_in, const int* in_sizes, int n_in,
                              void* d_out, int out_size, void* d_ws, size_t ws_size,
                              hipStream_t stream) {
    const float* k  = (const float*)d_in[0];
    const float* v  = (const float*)d_in[1];
    const float* rc = (const float*)d_in[2];
    const float* rs = (const float*)d_in[3];
    float* outk = (float*)d_out;
    float* outv = outk + KELEMS;

    hipLaunchKernelGGL(sinkrope_kernel, dim3(64 + 508, 128), dim3(256), 0, stream,
                       k, v, rc, rs, outk, outv);
}